// Round 1
// baseline (4662.490 us; speedup 1.0000x reference)
//
#include <hip/hip_runtime.h>
#include <math.h>

#define NROWS 8192
#define DIM   512
#define EPSF  1e-8f
#define SCALE 0.04419417382415922f   // 1/sqrt(512)

#define BM 32
#define BN 128

// ---------------- kernel 1: y = |x @ W| for W in {Wq,Wk,Wv} ----------------
// 64x64 output tile, BK=16, 256 threads (16x16), 4x4 micro-tile.
__global__ __launch_bounds__(256) void proj_kernel(
    const float* __restrict__ x,
    const float* __restrict__ Wq,
    const float* __restrict__ Wk,
    const float* __restrict__ Wv,
    float* __restrict__ qo,
    float* __restrict__ ko,
    float* __restrict__ vo)
{
    const float* W;
    float* y;
    if (blockIdx.z == 0)      { W = Wq; y = qo; }
    else if (blockIdx.z == 1) { W = Wk; y = ko; }
    else                      { W = Wv; y = vo; }

    const int bn  = blockIdx.x * 64;
    const int bm  = blockIdx.y * 64;
    const int tid = threadIdx.x;
    const int tx  = tid & 15;
    const int ty  = tid >> 4;

    __shared__ __align__(16) float Xt[16][68];   // [kk][m] (transposed)
    __shared__ __align__(16) float Ws[16][68];   // [kk][n]

    float acc[4][4] = {};

    const int xr = tid >> 2;          // 0..63 : x row
    const int xk = (tid & 3) * 4;     // 0,4,8,12 : kk base
    const int wr = tid >> 4;          // 0..15 : W row (kk)
    const int wc = (tid & 15) * 4;    // 0..60 : W col

    for (int k0 = 0; k0 < DIM; k0 += 16) {
        float4 xv = *(const float4*)(x + (size_t)(bm + xr) * DIM + k0 + xk);
        float4 wv = *(const float4*)(W + (size_t)(k0 + wr) * DIM + bn + wc);
        __syncthreads();
        Xt[xk + 0][xr] = xv.x;
        Xt[xk + 1][xr] = xv.y;
        Xt[xk + 2][xr] = xv.z;
        Xt[xk + 3][xr] = xv.w;
        *(float4*)&Ws[wr][wc] = wv;
        __syncthreads();
        #pragma unroll
        for (int kk = 0; kk < 16; kk++) {
            float4 a = *(const float4*)&Xt[kk][ty * 4];
            float4 b = *(const float4*)&Ws[kk][tx * 4];
            float av[4] = {a.x, a.y, a.z, a.w};
            float bv[4] = {b.x, b.y, b.z, b.w};
            #pragma unroll
            for (int i = 0; i < 4; i++)
                #pragma unroll
                for (int j = 0; j < 4; j++)
                    acc[i][j] = fmaf(av[i], bv[j], acc[i][j]);
        }
    }
    #pragma unroll
    for (int i = 0; i < 4; i++) {
        float4 o;
        o.x = fabsf(acc[i][0]);
        o.y = fabsf(acc[i][1]);
        o.z = fabsf(acc[i][2]);
        o.w = fabsf(acc[i][3]);
        *(float4*)(y + (size_t)(bm + ty * 4 + i) * DIM + bn + tx * 4) = o;
    }
}

// ---------------- kernel 2: fused unstabilized-softmax attention ----------------
// Per block: 32 Q rows. Loop K-tiles of 128 rows:
//   S[32][128] = Q @ K^T (D chunked by 64 through transposed LDS)
//   P = exp(S*SCALE), accumulate row sums in regs, P -> LDS (transposed)
//   O[32][512] += P @ V (V streamed through LDS, 8 rows at a time)
// Epilogue: shuffle-reduce row sums, out = O / (sum + eps).
__global__ __launch_bounds__(256) void flash_kernel(
    const float* __restrict__ q,
    const float* __restrict__ k,
    const float* __restrict__ v,
    float* __restrict__ out)
{
    const int qm0 = blockIdx.x * BM;
    const int tid = threadIdx.x;
    const int rg  = tid >> 5;      // 0..7  -> Q rows rg*4..+3 (phases A,B,C, epilogue)
    const int cg  = tid & 31;      // phase A: S cols cg*4..+3 ; phase C: O cols cg*16..+15

    __shared__ __align__(16) float Qt[64][36];    // [kk][qrow]
    __shared__ __align__(16) float Kt[64][132];   // [kk][krow]
    __shared__ __align__(16) float Pt[BN][36];    // [kcol][qrow]
    __shared__ __align__(16) float Vs[8][512];    // [krow][col]
    __shared__ float lsum[BM];

    float O[4][16]  = {};
    float lpart[4]  = {};

    const int qr  = tid >> 3;          // 0..31
    const int qk  = (tid & 7) * 4;     // 0..28
    const int kr_ = tid >> 2;          // 0..63
    const int kq  = (tid & 3) * 4;     // 0,4,8,12
    const int vr  = tid >> 5;          // 0..7
    const int vc  = (tid & 31) * 4;    // 0..124

    for (int kt = 0; kt < NROWS / BN; kt++) {
        const int kn0 = kt * BN;
        float S[4][4] = {};

        // ---- Phase A: S = Q @ K^T over D in chunks of 64 ----
        for (int kc = 0; kc < DIM; kc += 64) {
            float4 qv[2];
            #pragma unroll
            for (int j = 0; j < 2; j++)
                qv[j] = *(const float4*)(q + (size_t)(qm0 + qr) * DIM + kc + qk + j * 32);
            float4 kv[2][4];
            #pragma unroll
            for (int h = 0; h < 2; h++)
                #pragma unroll
                for (int j = 0; j < 4; j++)
                    kv[h][j] = *(const float4*)(k + (size_t)(kn0 + h * 64 + kr_) * DIM + kc + kq + j * 16);
            __syncthreads();
            #pragma unroll
            for (int j = 0; j < 2; j++) {
                Qt[qk + j * 32 + 0][qr] = qv[j].x;
                Qt[qk + j * 32 + 1][qr] = qv[j].y;
                Qt[qk + j * 32 + 2][qr] = qv[j].z;
                Qt[qk + j * 32 + 3][qr] = qv[j].w;
            }
            #pragma unroll
            for (int h = 0; h < 2; h++)
                #pragma unroll
                for (int j = 0; j < 4; j++) {
                    Kt[kq + j * 16 + 0][h * 64 + kr_] = kv[h][j].x;
                    Kt[kq + j * 16 + 1][h * 64 + kr_] = kv[h][j].y;
                    Kt[kq + j * 16 + 2][h * 64 + kr_] = kv[h][j].z;
                    Kt[kq + j * 16 + 3][h * 64 + kr_] = kv[h][j].w;
                }
            __syncthreads();
            #pragma unroll 8
            for (int kk = 0; kk < 64; kk++) {
                float4 a = *(const float4*)&Qt[kk][rg * 4];
                float4 b = *(const float4*)&Kt[kk][cg * 4];
                float av[4] = {a.x, a.y, a.z, a.w};
                float bv[4] = {b.x, b.y, b.z, b.w};
                #pragma unroll
                for (int i = 0; i < 4; i++)
                    #pragma unroll
                    for (int j = 0; j < 4; j++)
                        S[i][j] = fmaf(av[i], bv[j], S[i][j]);
            }
        }

        // ---- Phase B: P = exp(S * SCALE); row partial sums; P -> LDS ----
        float P[4][4];
        #pragma unroll
        for (int i = 0; i < 4; i++) {
            #pragma unroll
            for (int j = 0; j < 4; j++)
                P[i][j] = __expf(S[i][j] * SCALE);
            lpart[i] += (P[i][0] + P[i][1]) + (P[i][2] + P[i][3]);
        }
        #pragma unroll
        for (int i = 0; i < 4; i++)
            #pragma unroll
            for (int j = 0; j < 4; j++)
                Pt[cg * 4 + j][rg * 4 + i] = P[i][j];
        // (visibility of Pt is guaranteed by the barrier before the first phase-C compute)

        // ---- Phase C: O += P @ V, V streamed 8 rows at a time ----
        for (int jc = 0; jc < BN / 8; jc++) {
            float4 vv[4];
            #pragma unroll
            for (int w = 0; w < 4; w++)
                vv[w] = *(const float4*)(v + (size_t)(kn0 + jc * 8 + vr) * DIM + vc + w * 128);
            __syncthreads();   // prev subchunk's Vs reads done (and, for jc=0, Pt stores fenced)
            #pragma unroll
            for (int w = 0; w < 4; w++)
                *(float4*)&Vs[vr][vc + w * 128] = vv[w];
            __syncthreads();
            #pragma unroll 2
            for (int j = 0; j < 8; j++) {
                float4 p4 = *(const float4*)&Pt[jc * 8 + j][rg * 4];
                float pv[4] = {p4.x, p4.y, p4.z, p4.w};
                #pragma unroll
                for (int w = 0; w < 4; w++) {
                    float4 v4 = *(const float4*)&Vs[j][cg * 16 + w * 4];
                    float vl[4] = {v4.x, v4.y, v4.z, v4.w};
                    #pragma unroll
                    for (int i = 0; i < 4; i++)
                        #pragma unroll
                        for (int l = 0; l < 4; l++)
                            O[i][w * 4 + l] = fmaf(pv[i], vl[l], O[i][w * 4 + l]);
                }
            }
        }
    }

    // ---- Epilogue: reduce row sums across the 32 col-threads, normalize, store ----
    #pragma unroll
    for (int i = 0; i < 4; i++) {
        float s = lpart[i];
        #pragma unroll
        for (int m = 1; m < 32; m <<= 1)
            s += __shfl_xor(s, m, 64);
        lpart[i] = s;
    }
    if (cg == 0) {
        #pragma unroll
        for (int i = 0; i < 4; i++)
            lsum[rg * 4 + i] = lpart[i];
    }
    __syncthreads();
    #pragma unroll
    for (int i = 0; i < 4; i++) {
        float inv = 1.0f / (lsum[rg * 4 + i] + EPSF);
        #pragma unroll
        for (int w = 0; w < 4; w++) {
            float4 o4;
            o4.x = O[i][w * 4 + 0] * inv;
            o4.y = O[i][w * 4 + 1] * inv;
            o4.z = O[i][w * 4 + 2] * inv;
            o4.w = O[i][w * 4 + 3] * inv;
            *(float4*)(out + (size_t)(qm0 + rg * 4 + i) * DIM + cg * 16 + w * 4) = o4;
        }
    }
}

extern "C" void kernel_launch(void* const* d_in, const int* in_sizes, int n_in,
                              void* d_out, int out_size, void* d_ws, size_t ws_size,
                              hipStream_t stream) {
    const float* x  = (const float*)d_in[0];
    const float* Wq = (const float*)d_in[1];
    const float* Wk = (const float*)d_in[2];
    const float* Wv = (const float*)d_in[3];
    float* out = (float*)d_out;

    float* q = (float*)d_ws;                       // 16 MB
    float* k = q + (size_t)NROWS * DIM;            // 16 MB
    float* v = k + (size_t)NROWS * DIM;            // 16 MB

    dim3 pgrid(DIM / 64, NROWS / 64, 3);
    proj_kernel<<<pgrid, 256, 0, stream>>>(x, Wq, Wk, Wv, q, k, v);

    flash_kernel<<<NROWS / BM, 256, 0, stream>>>(q, k, v, out);
}

// Round 2
// 769.404 us; speedup vs baseline: 6.0599x; 6.0599x over previous
//
#include <hip/hip_runtime.h>
#include <hip/hip_bf16.h>
#include <math.h>

typedef unsigned short u16;
typedef __attribute__((ext_vector_type(8))) short short8;   // bf16x8 MFMA frag
typedef __attribute__((ext_vector_type(4))) float f32x4;    // fp32x4 acc frag

#define NROWS 8192
#define DIM   512
#define BM    32
#define BN    128
#define NKT   (NROWS / BN)          // 64
#define L2E_SCALE 0.063758716f      // log2(e) / sqrt(512)
#define EPSF  1e-8f

// ---- fp32 -> bf16 (RNE) ----
__device__ __forceinline__ u16 f2b(float x) {
    union { float f; unsigned u; } a; a.f = x;
    unsigned r = (a.u + 0x7fffu + ((a.u >> 16) & 1u)) >> 16;
    return (u16)r;
}

// ---- async global -> LDS, 16B per lane ----
__device__ __forceinline__ void ld16(const void* g, void* l) {
    __builtin_amdgcn_global_load_lds(
        (const __attribute__((address_space(1))) void*)g,
        (__attribute__((address_space(3))) void*)l, 16, 0, 0);
}

// ================= kernel 1: q,k = |x@W| (bf16, row-major); vt = |x@Wv|^T =================
__global__ __launch_bounds__(256) void proj_kernel(
    const float* __restrict__ x,
    const float* __restrict__ Wq,
    const float* __restrict__ Wk,
    const float* __restrict__ Wv,
    u16* __restrict__ qo,
    u16* __restrict__ ko,
    u16* __restrict__ vto)
{
    const float* W = (blockIdx.z == 0) ? Wq : (blockIdx.z == 1) ? Wk : Wv;

    const int bn  = blockIdx.x * 64;
    const int bm  = blockIdx.y * 64;
    const int tid = threadIdx.x;
    const int tx  = tid & 15;
    const int ty  = tid >> 4;

    __shared__ __align__(16) float Xt[16][68];   // [kk][m]
    __shared__ __align__(16) float Ws[16][68];   // [kk][n]

    float acc[4][4] = {};

    const int xr = tid >> 2;
    const int xk = (tid & 3) * 4;
    const int wr = tid >> 4;
    const int wc = (tid & 15) * 4;

    for (int k0 = 0; k0 < DIM; k0 += 16) {
        float4 xv = *(const float4*)(x + (size_t)(bm + xr) * DIM + k0 + xk);
        float4 wv = *(const float4*)(W + (size_t)(k0 + wr) * DIM + bn + wc);
        __syncthreads();
        Xt[xk + 0][xr] = xv.x; Xt[xk + 1][xr] = xv.y;
        Xt[xk + 2][xr] = xv.z; Xt[xk + 3][xr] = xv.w;
        *(float4*)&Ws[wr][wc] = wv;
        __syncthreads();
        #pragma unroll
        for (int kk = 0; kk < 16; kk++) {
            float4 a = *(const float4*)&Xt[kk][ty * 4];
            float4 b = *(const float4*)&Ws[kk][tx * 4];
            float av[4] = {a.x, a.y, a.z, a.w};
            float bv[4] = {b.x, b.y, b.z, b.w};
            #pragma unroll
            for (int i = 0; i < 4; i++)
                #pragma unroll
                for (int j = 0; j < 4; j++)
                    acc[i][j] = fmaf(av[i], bv[j], acc[i][j]);
        }
    }

    if (blockIdx.z == 2) {
        // vt[col][row], pack 4 consecutive rows (i) into one 8B store
        #pragma unroll
        for (int j = 0; j < 4; j++) {
            unsigned long long pk = 0;
            #pragma unroll
            for (int i = 0; i < 4; i++)
                pk |= (unsigned long long)f2b(fabsf(acc[i][j])) << (16 * i);
            *(unsigned long long*)(vto + (size_t)(bn + tx * 4 + j) * NROWS + bm + ty * 4) = pk;
        }
    } else {
        u16* y = (blockIdx.z == 0) ? qo : ko;
        #pragma unroll
        for (int i = 0; i < 4; i++) {
            unsigned long long pk = 0;
            #pragma unroll
            for (int j = 0; j < 4; j++)
                pk |= (unsigned long long)f2b(fabsf(acc[i][j])) << (16 * j);
            *(unsigned long long*)(y + (size_t)(bm + ty * 4 + i) * DIM + bn + tx * 4) = pk;
        }
    }
}

// ================= kernel 2: fused attention, bf16 MFMA =================
// Block: 32 Q-rows, 512 threads = 8 waves. Q in registers (A-frags).
// Per K-tile (BN=128): S = Q@K^T via 2x 64KB K d-chunks; P=exp2(S*c) -> LDS;
// O += P@V via 2x 64KB Vt krow-slabs. Double-buffered global_load_lds staging
// with XOR-swizzled source addresses (conflict-free b128 reads).
__global__ __launch_bounds__(512, 2) void flash_kernel(
    const u16* __restrict__ q,
    const u16* __restrict__ k,
    const u16* __restrict__ vt,
    float* __restrict__ out)
{
    __shared__ __align__(16) u16 buf[2][32768];     // 2 x 64 KB staging
    __shared__ __align__(16) u16 plds[BM * BN];     // 8 KB  P tile (swizzled)
    __shared__ float sums_s[8][BM];
    __shared__ float inv_s[BM];

    const int tid  = threadIdx.x;
    const int w    = tid >> 6;       // wave 0..7
    const int lane = tid & 63;
    const int nm   = lane & 15;
    const int quad = lane >> 4;
    const int qm0  = blockIdx.x * BM;

    // ---- Q fragments in registers: A[m=nm][d = s*32 + quad*8 + j] ----
    short8 Qf[2][16];
    #pragma unroll
    for (int rt = 0; rt < 2; rt++)
        #pragma unroll
        for (int s = 0; s < 16; s++)
            Qf[rt][s] = *(const short8*)(q + (size_t)(qm0 + rt * 16 + nm) * DIM + s * 32 + quad * 8);

    f32x4 O[2][4] = {};      // [rowtile][coltile]: O rows rt*16+quad*4+i, cols w*64+ct*16+nm
    float rsum[2][4] = {};

    // ---- staging helpers: 64KB each, 8 x (512 threads x 16B) sweeps ----
    auto stage_k = [&](int bi, int kn0, int dc) {   // K rows kn0..+128, d dc..+256 ; LDS row=512B
        #pragma unroll
        for (int i = 0; i < 8; i++) {
            int lo = i * 8192 + tid * 16;           // byte offset in buffer
            int r  = lo >> 9;                       // 0..127
            int gp = (lo >> 4) & 31;                // granule-in-row
            int g  = gp ^ (r & 7);                  // source granule (swizzle)
            ld16(k + (size_t)(kn0 + r) * DIM + dc + g * 8, (u16*)buf[bi] + (lo >> 1));
        }
    };
    auto stage_v = [&](int bi, int kn0, int sc) {   // Vt rows(=dcols) 0..512, krows kn0+sc*64..+64 ; LDS row=128B
        #pragma unroll
        for (int i = 0; i < 8; i++) {
            int lo = i * 8192 + tid * 16;
            int dcol = lo >> 7;                     // 0..511
            int gp = (lo >> 4) & 7;
            int g  = gp ^ (dcol & 7);
            ld16(vt + (size_t)dcol * NROWS + kn0 + sc * 64 + g * 8, (u16*)buf[bi] + (lo >> 1));
        }
    };

    stage_k(0, 0, 0);

    for (int kt = 0; kt < NKT; kt++) {
        const int kn0 = kt * BN;
        f32x4 S[2] = {};

        // ---- Phase A: S = Q @ K^T  (2 d-chunks of 256) ----
        #pragma unroll
        for (int c = 0; c < 2; c++) {
            __syncthreads();                         // drains prefetch into buf[c]
            if (c == 0) stage_k(1, kn0, 256);
            else        stage_v(0, kn0, 0);
            const u16* bk = buf[c];
            const int row = w * 16 + nm;             // this wave's K-row (= S col)
            #pragma unroll
            for (int s = 0; s < 8; s++) {
                const short8 Kf = *(const short8*)(bk + row * 256 + (((s * 4 + quad) ^ (row & 7)) << 3));
                S[0] = __builtin_amdgcn_mfma_f32_16x16x32_bf16(Qf[0][c * 8 + s], Kf, S[0], 0, 0, 0);
                S[1] = __builtin_amdgcn_mfma_f32_16x16x32_bf16(Qf[1][c * 8 + s], Kf, S[1], 0, 0, 0);
            }
        }

        // ---- Phase B: P = exp2(S * L2E_SCALE); rowsums; P -> LDS (A-layout, swizzled) ----
        {
            const int pcol = w * 16 + nm;
            const int pgw  = pcol >> 3;
            const int pcl  = pcol & 7;
            #pragma unroll
            for (int rt = 0; rt < 2; rt++)
                #pragma unroll
                for (int i = 0; i < 4; i++) {
                    float p = exp2f(S[rt][i] * L2E_SCALE);
                    rsum[rt][i] += p;
                    const int prow = rt * 16 + quad * 4 + i;
                    plds[prow * 128 + ((pgw ^ (prow & 7)) << 3) + pcl] = f2b(p);
                }
        }

        // ---- Phase C: O += P @ V  (2 krow-slabs of 64) ----
        #pragma unroll
        for (int sc = 0; sc < 2; sc++) {
            __syncthreads();                         // drains prefetch into buf[sc]; fences plds
            if (sc == 0)            stage_v(1, kn0, 1);
            else if (kt + 1 < NKT)  stage_k(0, kn0 + BN, 0);
            const u16* bv = buf[sc];
            #pragma unroll
            for (int kk = 0; kk < 2; kk++) {
                short8 Pf[2];
                #pragma unroll
                for (int rt = 0; rt < 2; rt++) {
                    const int prow = rt * 16 + nm;
                    Pf[rt] = *(const short8*)(plds + prow * 128 + (((sc * 8 + kk * 4 + quad) ^ (prow & 7)) << 3));
                }
                #pragma unroll
                for (int ct = 0; ct < 4; ct++) {
                    const int dcol = w * 64 + ct * 16 + nm;
                    const short8 Vf = *(const short8*)(bv + dcol * 64 + (((kk * 4 + quad) ^ (dcol & 7)) << 3));
                    O[0][ct] = __builtin_amdgcn_mfma_f32_16x16x32_bf16(Pf[0], Vf, O[0][ct], 0, 0, 0);
                    O[1][ct] = __builtin_amdgcn_mfma_f32_16x16x32_bf16(Pf[1], Vf, O[1][ct], 0, 0, 0);
                }
            }
        }
    }

    // ---- Epilogue: reduce row sums (16 lanes x 8 waves), normalize, store ----
    float rtot[2][4];
    #pragma unroll
    for (int rt = 0; rt < 2; rt++)
        #pragma unroll
        for (int i = 0; i < 4; i++) {
            float s = rsum[rt][i];
            s += __shfl_xor(s, 1);
            s += __shfl_xor(s, 2);
            s += __shfl_xor(s, 4);
            s += __shfl_xor(s, 8);
            rtot[rt][i] = s;
        }
    if (nm == 0) {
        #pragma unroll
        for (int rt = 0; rt < 2; rt++)
            #pragma unroll
            for (int i = 0; i < 4; i++)
                sums_s[w][rt * 16 + quad * 4 + i] = rtot[rt][i];
    }
    __syncthreads();
    if (tid < BM) {
        float t = 0.f;
        #pragma unroll
        for (int ww = 0; ww < 8; ww++) t += sums_s[ww][tid];
        inv_s[tid] = 1.0f / (t + EPSF);
    }
    __syncthreads();
    #pragma unroll
    for (int rt = 0; rt < 2; rt++)
        #pragma unroll
        for (int i = 0; i < 4; i++) {
            const int row = rt * 16 + quad * 4 + i;
            const float inv = inv_s[row];
            #pragma unroll
            for (int ct = 0; ct < 4; ct++)
                out[(size_t)(qm0 + row) * DIM + w * 64 + ct * 16 + nm] = O[rt][ct][i] * inv;
        }
}

extern "C" void kernel_launch(void* const* d_in, const int* in_sizes, int n_in,
                              void* d_out, int out_size, void* d_ws, size_t ws_size,
                              hipStream_t stream) {
    const float* x  = (const float*)d_in[0];
    const float* Wq = (const float*)d_in[1];
    const float* Wk = (const float*)d_in[2];
    const float* Wv = (const float*)d_in[3];
    float* out = (float*)d_out;

    u16* q  = (u16*)d_ws;                         // 8 MB
    u16* kk = q + (size_t)NROWS * DIM;            // 8 MB
    u16* vt = kk + (size_t)NROWS * DIM;           // 8 MB (transposed: [DIM][NROWS])

    dim3 pgrid(DIM / 64, NROWS / 64, 3);
    proj_kernel<<<pgrid, 256, 0, stream>>>(x, Wq, Wk, Wv, q, kk, vt);

    flash_kernel<<<NROWS / BM, 512, 0, stream>>>(q, kk, vt, out);
}